// Round 6
// baseline (807.752 us; speedup 1.0000x reference)
//
#include <hip/hip_runtime.h>

// LSTM (B=2048, T=1024, I=8, H=64) + sigmoid(FC), bf16 MFMA, in-register
// activations, duplicate-column split — R=2, 4 BLOCKS/CU occupancy revision.
//
// r1-r5 lesson: every inner-loop restructure (raw barriers, exp2f, dual
// chain, half-step pipeline, split accumulators) regressed; r0's loop body
// + multi-block overlap is the winning schedule. The one untried lever is
// occupancy: r0 ran 2 blocks/CU and its 1116-cy step wall is ~50% stall
// (issue per SIMD only ~450-600 cy). This revision keeps the r0 inner loop
// BYTE-IDENTICAL and changes only the decomposition: R=2 batch rows/block
// -> grid 1024 -> 4 blocks/CU -> 4 independent LSTM chains per SIMD filling
// each other's barrier/ds_read/exp stalls. MFMA work doubles chip-wide
// (8x column duplication instead of 4x) but the MFMA pipe is only ~60
// cy/wave/step — nowhere near saturation.
//
// Kept: __expf activations + manual f2bf (r2: exp2f lowers to slow ocml),
// plain __syncthreads, no unroll pragma, bias in K-slot ch8.
// HP=80 (not r0's 40: 40 aliases h rows since jh reaches 63; 80 is
// correctness-clean, verified in r2/r5 at absmax 0.0039, <=2-way banks).

namespace {
constexpr int T_LEN = 1024;
constexpr int R     = 2;    // batch rows per block
constexpr int TS    = 32;   // timesteps of x per staged chunk
constexpr int HP    = 80;   // h_lds row stride in shorts (160 B, 16B-aligned)

typedef __attribute__((ext_vector_type(8))) short  short8v;
typedef __attribute__((ext_vector_type(4))) float  float4v;
typedef unsigned short u16;
typedef unsigned long long u64;

__device__ __forceinline__ float fsig(float x) {
  return __builtin_amdgcn_rcpf(1.f + __expf(-x));
}
__device__ __forceinline__ float ftanh(float x) {
  return 1.f - 2.f * __builtin_amdgcn_rcpf(__expf(2.f * x) + 1.f);
}
__device__ __forceinline__ u16 f2bf(float f) {  // RNE
  unsigned int u = __float_as_uint(f);
  unsigned int r = ((u >> 16) & 1u) + 0x7fffu;
  return (u16)((u + r) >> 16);
}

__global__ __launch_bounds__(256, 4) void lstm_split(
    const float* __restrict__ x,     // [B, T, 8]
    const float* __restrict__ W_ih,  // [256, 8]
    const float* __restrict__ W_hh,  // [256, 64]
    const float* __restrict__ b_ih,  // [256]
    const float* __restrict__ b_hh,  // [256]
    const float* __restrict__ fc_w,  // [64]
    const float* __restrict__ fc_b,  // [1]
    float* __restrict__ out) {       // [B]
  __shared__ __align__(16) u16   x_lds[2][TS][R][32];  // 8 KB; full K-rows
  __shared__ __align__(16) u16   h_lds[2][R][HP];      // 640 B
  __shared__ __align__(16) float hf[R][64];            // final h (fp32)

  const int tid  = threadIdx.x;
  const int lane = tid & 63;
  const int wv   = tid >> 6;       // wave 0..3
  const int g4   = lane >> 4;      // MFMA k-quad / C row-quad
  const int nib  = lane & 15;      // MFMA m/n coord
  const int row  = nib & 1;        // batch row (8x column duplication)
  const int rsel = nib >> 2;       // which acc reg this thread activates
  const int jh   = 16 * wv + 4 * g4 + rsel;  // owned h index
  const int bBase = blockIdx.x * R;

  // ---- static A fragments: wave wv holds tiles {4g+wv}, g=0..3 (i,f,g,o) ----
  // A[m=16*(4g+wv)+nib][k=8*g4+j]; frag0 k=0..31 = [W_ih(8)|bias|0...],
  // frag1 = W_hh[:,0:32], frag2 = W_hh[:,32:64].
  short8v a0[4], a1[4], a2[4];
  for (int g = 0; g < 4; ++g) {
    const int n = 64 * g + 16 * wv + nib;  // gate row
    short8v f0, f1, f2;
    for (int j = 0; j < 8; ++j) {
      const int k = 8 * g4 + j;
      float v0 = 0.f;
      if (k < 8) v0 = W_ih[n * 8 + k];
      else if (k == 8) v0 = b_ih[n] + b_hh[n];
      f0[j] = (short)f2bf(v0);
      f1[j] = (short)f2bf(W_hh[n * 64 + k]);
      f2[j] = (short)f2bf(W_hh[n * 64 + 32 + k]);
    }
    a0[g] = f0; a1[g] = f1; a2[g] = f2;
  }

  // ---- LDS init: h0 = 0 (both bufs); x constant channels once per buf ----
  for (int i = tid; i < 2 * R * HP; i += 256) ((u16*)h_lds)[i] = 0;
  if (tid < 2 * TS * R) {  // 128 entries: 2 bufs x 32 tt x 2 rows
    const int buf = tid >> 6, rem = tid & 63, tt = rem >> 1, rr = rem & 1;
    u16* p = &x_lds[buf][tt][rr][0];
    p[8] = 0x3f80;  // bias channel = 1.0
    for (int chn = 9; chn < 32; ++chn) p[chn] = 0;
  }

  // ---- x staging: tid<128, 1 float4/thread/chunk, double-buffered ----
  // per chunk: 2 rows x 32 tt x 8 ch x 4 B = 2 KB = 128 float4.
  float4v xr;
  const int sr = tid >> 6, sm = tid & 63;          // src row, float4 idx
  const int stt = sm >> 1, sch = (sm & 1) * 4;     // dest tt, channel
  const bool stager = (tid < 128);                 // waves 0-1 (wave-uniform)
  auto stage_load = [&](int chunk) {
    if (stager) {
      const float* src = x + ((size_t)bBase + sr) * (T_LEN * 8) +
                         (size_t)chunk * (TS * 8);
      xr = *(const float4v*)&src[sm * 4];
    }
  };
  auto stage_write = [&](int buf) {
    if (stager) {
      union { u64 u; u16 s[4]; } p;
      p.s[0] = f2bf(xr[0]); p.s[1] = f2bf(xr[1]);
      p.s[2] = f2bf(xr[2]); p.s[3] = f2bf(xr[3]);
      *(u64*)&x_lds[buf][stt][sr][sch] = p.u;
    }
  };

  stage_load(0);
  stage_write(0);
  __syncthreads();

  // hoisted select masks for the cndmask tree
  const bool sel1 = (rsel & 1) != 0;
  const bool sel2 = (rsel & 2) != 0;
  float c = 0.f;

  for (int ch = 0; ch < T_LEN / TS; ++ch) {
    const int xb = ch & 1;
    const bool more = (ch < T_LEN / TS - 1);
    for (int tt = 0; tt < TS; ++tt) {
      const int t = ch * TS + tt;
      const int hb = t & 1;
      if (tt == 0 && more) stage_load(ch + 1);  // reg loads; drain in stage_write

      // ---- B fragments (uniform b128 reads) ----
      const short8v fx  = *(const short8v*)&x_lds[xb][tt][row][8 * g4];
      const short8v fh0 = *(const short8v*)&h_lds[hb][row][8 * g4];
      const short8v fh1 = *(const short8v*)&h_lds[hb][row][32 + 8 * g4];

      // ---- 12 MFMAs: 4 gate-quads x (x | h-lo | h-hi) ----
      float4v acc[4];
#pragma unroll
      for (int g = 0; g < 4; ++g)
        acc[g] = __builtin_amdgcn_mfma_f32_16x16x32_bf16(
            a0[g], fx, (float4v){0.f, 0.f, 0.f, 0.f}, 0, 0, 0);
#pragma unroll
      for (int g = 0; g < 4; ++g)
        acc[g] = __builtin_amdgcn_mfma_f32_16x16x32_bf16(a1[g], fh0, acc[g], 0, 0, 0);
#pragma unroll
      for (int g = 0; g < 4; ++g)
        acc[g] = __builtin_amdgcn_mfma_f32_16x16x32_bf16(a2[g], fh1, acc[g], 0, 0, 0);

      // ---- pick this thread's element (reg-select tree) and activate ----
      float gsel[4];
#pragma unroll
      for (int g = 0; g < 4; ++g) {
        const float x01 = sel1 ? acc[g][1] : acc[g][0];
        const float x23 = sel1 ? acc[g][3] : acc[g][2];
        gsel[g] = sel2 ? x23 : x01;
      }
      const float iv = fsig(gsel[0]);
      const float fv = fsig(gsel[1]);
      const float gv = ftanh(gsel[2]);
      const float ov = fsig(gsel[3]);
      c = fv * c + iv * gv;
      const float h = ov * ftanh(c);
      h_lds[hb ^ 1][row][jh] = f2bf(h);  // duplicate lanes write same value
      if (t == T_LEN - 1) hf[row][jh] = h;
      if (tt == TS - 1 && more) stage_write((ch + 1) & 1);
      __syncthreads();  // one barrier per step
    }
  }

  // ---- epilogue: out[b] = sigmoid(hT . fc_w + fc_b) ----
  if (tid < R) {
    float a = fc_b[0];
#pragma unroll
    for (int k = 0; k < 64; ++k) a += hf[tid][k] * fc_w[k];
    out[bBase + tid] = fsig(a);
  }
}
}  // namespace

extern "C" void kernel_launch(void* const* d_in, const int* in_sizes, int n_in,
                              void* d_out, int out_size, void* d_ws,
                              size_t ws_size, hipStream_t stream) {
  const float* x    = (const float*)d_in[0];
  const float* W_ih = (const float*)d_in[1];
  const float* W_hh = (const float*)d_in[2];
  const float* b_ih = (const float*)d_in[3];
  const float* b_hh = (const float*)d_in[4];
  const float* fc_w = (const float*)d_in[5];
  const float* fc_b = (const float*)d_in[6];
  float* out = (float*)d_out;

  const int B = in_sizes[0] / (T_LEN * 8);  // 2048
  lstm_split<<<dim3(B / R), dim3(256), 0, stream>>>(x, W_ih, W_hh, b_ih, b_hh,
                                                    fc_w, fc_b, out);
}

// Round 7
// 786.103 us; speedup vs baseline: 1.0275x; 1.0275x over previous
//
#include <hip/hip_runtime.h>

// LSTM (B=2048, T=1024, I=8, H=64) + sigmoid(FC) — WAVE-AUTONOMOUS revision:
// no barriers, no __shared__, h recirculated in-register via ds_bpermute.
//
// r0-r6 diagnosis: per-step __syncthreads + LDS h round-trip phase-locks all
// co-resident waves (VALUBusy capped ~69% even at 4 waves/SIMD, r6) and
// exposes a ~500cy serial chain per step. This kernel deletes the exchange:
// MFMA operands are SWAPPED vs r0 — A (M-side) = batch data [x|h] (2 rows x
// 8 dup), B (N-side) = weights (16 n-tiles x 256 gate rows, resident in 192
// VGPRs). C-layout: acc[n][r] = gate col 16n+nib for batch row r&1. Then
// gate g of h-index jh = lane lives at acc[4g+g4][rho] (g4-select tree, 24
// cndmask), and h[.][jh] is produced exactly at lane jh — next step's A
// h-fragments rebuild with 2 shfl_xor + 1 cvt_pk + 8 ds_bpermute, all
// intra-wave. Grid = 1024 single-wave blocks = 1 wave/SIMD, each free-
// running ~550-650cy/step with zero sync.
//
// Kept verified idioms: __expf activations (r2: exp2f lowers to slow ocml),
// manual f2bf for init, v_cvt_pk_bf16_f32 for the h repack (RNE).

namespace {
constexpr int T_LEN = 1024;

typedef __attribute__((ext_vector_type(8))) short  short8v;
typedef __attribute__((ext_vector_type(4))) float  float4v;
typedef unsigned short u16;
typedef unsigned int   u32;

__device__ __forceinline__ float fsig(float x) {
  return __builtin_amdgcn_rcpf(1.f + __expf(-x));
}
__device__ __forceinline__ float ftanh(float x) {
  return 1.f - 2.f * __builtin_amdgcn_rcpf(__expf(2.f * x) + 1.f);
}
__device__ __forceinline__ u16 f2bf(float f) {  // RNE (init only)
  u32 u = __float_as_uint(f);
  u32 r = ((u >> 16) & 1u) + 0x7fffu;
  return (u16)((u + r) >> 16);
}
__device__ __forceinline__ u32 pk_bf16(float lo, float hi) {  // 1 VALU, RNE
  u32 d;
  asm("v_cvt_pk_bf16_f32 %0, %1, %2" : "=v"(d) : "v"(lo), "v"(hi));
  return d;
}

__global__ __launch_bounds__(64, 1) void lstm_wave(
    const float* __restrict__ x,     // [B, T, 8]
    const float* __restrict__ W_ih,  // [256, 8]
    const float* __restrict__ W_hh,  // [256, 64]
    const float* __restrict__ b_ih,  // [256]
    const float* __restrict__ b_hh,  // [256]
    const float* __restrict__ fc_w,  // [64]
    const float* __restrict__ fc_b,  // [1]
    float* __restrict__ out) {       // [B]
  const int lane = threadIdx.x;   // 0..63; also the h-index this lane owns
  const int g4   = lane >> 4;     // K-quad of A/B frags; = jh>>4
  const int nib  = lane & 15;     // within-tile M/N coord
  const int rho  = nib & 1;       // batch row this lane's A-frags carry
  const int bBase = blockIdx.x * 2;

  // ---- B-side weights, resident: 16 n-tiles x {x+bias | h_lo | h_hi} ----
  // B[k=8*g4+j][col=16n+nib] = W[gi][k] (weights transposed into B role).
  short8v wx[16], wl[16], wh[16];
#pragma unroll
  for (int n = 0; n < 16; ++n) {
    const int gi = 16 * n + nib;  // gate row (i,f,g,o blocks of 64)
    short8v f0, f1, f2;
#pragma unroll
    for (int j = 0; j < 8; ++j) {
      const int k = 8 * g4 + j;
      float v0 = 0.f;
      if (k < 8) v0 = W_ih[gi * 8 + k];
      else if (k == 8) v0 = b_ih[gi] + b_hh[gi];  // bias via x-slot k=8
      f0[j] = (short)f2bf(v0);
      f1[j] = (short)f2bf(W_hh[gi * 64 + k]);
      f2[j] = (short)f2bf(W_hh[gi * 64 + 32 + k]);
    }
    wx[n] = f0; wl[n] = f1; wh[n] = f2;
  }

  // ---- constant part of the x A-frag: bias=1.0 at k=8 (g4==1, j==0) ----
  short8v fxc;
  {
    u32* p = (u32*)&fxc;
    p[0] = (g4 == 1) ? 0x00003f80u : 0u;  // bf16(1.0) in low half
    p[1] = p[2] = p[3] = 0u;
  }

  // ---- bpermute source addresses (bytes = 4*src_lane), precomputed ----
  // fh0[s] = h[rho][8*g4+2s .. +1]  -> produced at lane 8*g4+2s+rho
  // fh1[s] = h[rho][32+8*g4+2s ..]  -> +32 lanes -> +128 bytes
  int ba0[4], ba1[4];
#pragma unroll
  for (int s = 0; s < 4; ++s) {
    ba0[s] = 4 * (8 * g4 + 2 * s + rho);
    ba1[s] = ba0[s] + 128;
  }

  // ---- x prefetch (only g4==0 lanes carry x in their A-frag) ----
  const float* xptr = x + (size_t)(bBase + rho) * (T_LEN * 8);
  float4v xp0, xp1;
  if (g4 == 0) {
    xp0 = *(const float4v*)(xptr);
    xp1 = *(const float4v*)(xptr + 4);
  }

  // hoisted select masks (per-lane constants -> long-lived cndmask masks)
  const bool mg1 = (g4 & 1) != 0;
  const bool mg2 = (g4 & 2) != 0;
  const bool odd = (lane & 1) != 0;

  float h0 = 0.f, h1 = 0.f, c0 = 0.f, c1 = 0.f;  // rows 0,1 at jh = lane

  for (int t = 0; t < T_LEN; ++t) {
    // ---- rebuild A h-frags from h(t-1): all intra-wave, no barrier ----
    // Z[L] = pk(h_{L&1}[2*(L>>1)], h_{L&1}[2*(L>>1)+1])
    const float px0 = __shfl_xor(h0, 1);
    const float px1 = __shfl_xor(h1, 1);
    const u32 Z = pk_bf16(odd ? px1 : h0, odd ? h1 : px0);
    short8v fh0, fh1;
    {
      u32* q0 = (u32*)&fh0;
      u32* q1 = (u32*)&fh1;
#pragma unroll
      for (int s = 0; s < 4; ++s) {
        q0[s] = (u32)__builtin_amdgcn_ds_bpermute(ba0[s], (int)Z);
        q1[s] = (u32)__builtin_amdgcn_ds_bpermute(ba1[s], (int)Z);
      }
    }

    // ---- x A-frag for step t; prefetch t+1 ----
    short8v fx = fxc;
    if (g4 == 0) {
      u32* p = (u32*)&fx;
      p[0] = pk_bf16(xp0[0], xp0[1]);
      p[1] = pk_bf16(xp0[2], xp0[3]);
      p[2] = pk_bf16(xp1[0], xp1[1]);
      p[3] = pk_bf16(xp1[2], xp1[3]);
      if (t + 1 < T_LEN) {
        const float* s2 = xptr + (size_t)(t + 1) * 8;
        xp0 = *(const float4v*)(s2);
        xp1 = *(const float4v*)(s2 + 4);
      }
    }

    // ---- 48 MFMAs: A = batch frag (shared), B = per-tile weights ----
    float4v acc[16];
#pragma unroll
    for (int n = 0; n < 16; ++n)
      acc[n] = __builtin_amdgcn_mfma_f32_16x16x32_bf16(
          fx, wx[n], (float4v){0.f, 0.f, 0.f, 0.f}, 0, 0, 0);
#pragma unroll
    for (int n = 0; n < 16; ++n)
      acc[n] = __builtin_amdgcn_mfma_f32_16x16x32_bf16(fh0, wl[n], acc[n], 0, 0, 0);
#pragma unroll
    for (int n = 0; n < 16; ++n)
      acc[n] = __builtin_amdgcn_mfma_f32_16x16x32_bf16(fh1, wh[n], acc[n], 0, 0, 0);

    // ---- gate g of jh=lane, row r: acc[4g+g4][r] -> g4-select tree ----
    float gv0[4], gv1[4];
#pragma unroll
    for (int g = 0; g < 4; ++g) {
      const float a01_0 = mg1 ? acc[4 * g + 1][0] : acc[4 * g + 0][0];
      const float a23_0 = mg1 ? acc[4 * g + 3][0] : acc[4 * g + 2][0];
      gv0[g] = mg2 ? a23_0 : a01_0;
      const float a01_1 = mg1 ? acc[4 * g + 1][1] : acc[4 * g + 0][1];
      const float a23_1 = mg1 ? acc[4 * g + 3][1] : acc[4 * g + 2][1];
      gv1[g] = mg2 ? a23_1 : a01_1;
    }

    // ---- two independent cell updates (interleave hides exp latency) ----
    {
      const float iv = fsig(gv0[0]), fv = fsig(gv0[1]);
      const float gg = ftanh(gv0[2]), ov = fsig(gv0[3]);
      c0 = fv * c0 + iv * gg;
      h0 = ov * ftanh(c0);
    }
    {
      const float iv = fsig(gv1[0]), fv = fsig(gv1[1]);
      const float gg = ftanh(gv1[2]), ov = fsig(gv1[3]);
      c1 = fv * c1 + iv * gg;
      h1 = ov * ftanh(c1);
    }
  }

  // ---- epilogue: out[row] = sigmoid(hT . fc_w + fc_b), full-wave reduce ----
  const float w = fc_w[lane];
  float p0 = h0 * w, p1 = h1 * w;
#pragma unroll
  for (int m = 1; m < 64; m <<= 1) {
    p0 += __shfl_xor(p0, m);
    p1 += __shfl_xor(p1, m);
  }
  if (lane == 0) {
    const float b = fc_b[0];
    out[bBase + 0] = fsig(p0 + b);
    out[bBase + 1] = fsig(p1 + b);
  }
}
}  // namespace

extern "C" void kernel_launch(void* const* d_in, const int* in_sizes, int n_in,
                              void* d_out, int out_size, void* d_ws,
                              size_t ws_size, hipStream_t stream) {
  const float* x    = (const float*)d_in[0];
  const float* W_ih = (const float*)d_in[1];
  const float* W_hh = (const float*)d_in[2];
  const float* b_ih = (const float*)d_in[3];
  const float* b_hh = (const float*)d_in[4];
  const float* fc_w = (const float*)d_in[5];
  const float* fc_b = (const float*)d_in[6];
  float* out = (float*)d_out;

  const int B = in_sizes[0] / (T_LEN * 8);  // 2048
  lstm_wave<<<dim3(B / 2), dim3(64), 0, stream>>>(x, W_ih, W_hh, b_ih, b_hh,
                                                  fc_w, fc_b, out);
}

// Round 8
// 412.702 us; speedup vs baseline: 1.9572x; 1.9048x over previous
//
#include <hip/hip_runtime.h>

// LSTM (B=2048, T=1024, I=8, H=64) + sigmoid(FC), bf16 MFMA, in-register
// activations, duplicate-column split, 2 blocks/CU — ANTI-PHASE revision.
//
// Machine model (locked by r0/r6/r7 counters): one 16x16x32 bf16 MFMA costs
// ~19.4 cy/SIMD of matrix-pipe time. r0 per SIMD-step: 24 MFMA = 466 cy
// (MfmaUtil 38%) + 641 cy VALU (57%) = 1107 ~= the 1116-cy wall -> the two
// co-resident blocks are PHASE-LOCKED (both MFMA together, both activate
// together; each phase pipe-serialized). m114: MFMA and VALU pipes overlap
// when fed by different waves -> anti-phased blocks give wall ~max(641,466).
// This revision keeps the winning r0 loop body and adds a ONE-TIME ~384cy
// s_sleep stagger for half the blocks to seed anti-phase. Contention repels
// same-phase overlap, so the anti-phase should self-maintain.
// Stagger parity (blockIdx ^ blockIdx>>8)&1 splits co-resident pairs under
// both plausible mappings: (i, i+256) XCD-round-robin and (2i, 2i+1).
//
// HP=80 is a CORRECTNESS fix, not a tweak: r0's HP=40 aliased h rows
// (jh reaches 63), absmax 0.0078 vs 0.0039 fixed. __expf kept (r2: exp2f
// lowers to slow ocml, +22% VALU). h-store via v_cvt_pk_bf16_f32 (1 op,
// RNE, r2-verified). Plain __syncthreads (r1's asm barriers regressed).

namespace {
constexpr int T_LEN = 1024;
constexpr int R     = 4;    // batch rows per block
constexpr int TS    = 32;   // timesteps of x per staged chunk
constexpr int HP    = 80;   // h_lds row stride in shorts (160 B, 16B-aligned)

typedef __attribute__((ext_vector_type(8))) short  short8v;
typedef __attribute__((ext_vector_type(4))) float  float4v;
typedef unsigned short u16;
typedef unsigned long long u64;
typedef unsigned int u32;

__device__ __forceinline__ float fsig(float x) {
  return __builtin_amdgcn_rcpf(1.f + __expf(-x));
}
__device__ __forceinline__ float ftanh(float x) {
  return 1.f - 2.f * __builtin_amdgcn_rcpf(__expf(2.f * x) + 1.f);
}
__device__ __forceinline__ u16 f2bf(float f) {  // RNE (init-time only)
  u32 u = __float_as_uint(f);
  u32 r = ((u >> 16) & 1u) + 0x7fffu;
  return (u16)((u + r) >> 16);
}
__device__ __forceinline__ u16 cvt_bf16(float f) {  // 1 VALU op, RNE
  u32 d;
  asm("v_cvt_pk_bf16_f32 %0, %1, %2" : "=v"(d) : "v"(f), "v"(f));
  return (u16)d;
}

__global__ __launch_bounds__(256, 2) void lstm_split(
    const float* __restrict__ x,     // [B, T, 8]
    const float* __restrict__ W_ih,  // [256, 8]
    const float* __restrict__ W_hh,  // [256, 64]
    const float* __restrict__ b_ih,  // [256]
    const float* __restrict__ b_hh,  // [256]
    const float* __restrict__ fc_w,  // [64]
    const float* __restrict__ fc_b,  // [1]
    float* __restrict__ out) {       // [B]
  __shared__ __align__(16) u16   x_lds[2][TS][R][32];  // 16 KB; full K-rows
  __shared__ __align__(16) u16   h_lds[2][R][HP];      // 2.5 KB
  __shared__ __align__(16) float hf[R][64];            // final h (fp32)

  const int tid  = threadIdx.x;
  const int lane = tid & 63;
  const int wv   = tid >> 6;       // wave 0..3
  const int g4   = lane >> 4;      // MFMA k-quad / C row-quad
  const int nib  = lane & 15;      // MFMA m/n coord
  const int row  = nib & 3;        // batch row (cols 4..15 duplicate 0..3)
  const int rsel = nib >> 2;       // which acc reg this thread activates
  const int jh   = 16 * wv + 4 * g4 + rsel;  // owned h index
  const int bBase = blockIdx.x * R;

  // ---- static A fragments: wave wv holds tiles {4g+wv}, g=0..3 (i,f,g,o) ----
  // A[m=16*(4g+wv)+nib][k=8*g4+j]; frag0 k=0..31 = [W_ih(8)|bias|0...],
  // frag1 = W_hh[:,0:32], frag2 = W_hh[:,32:64].
  short8v a0[4], a1[4], a2[4];
  for (int g = 0; g < 4; ++g) {
    const int n = 64 * g + 16 * wv + nib;  // gate row
    short8v f0, f1, f2;
    for (int j = 0; j < 8; ++j) {
      const int k = 8 * g4 + j;
      float v0 = 0.f;
      if (k < 8) v0 = W_ih[n * 8 + k];
      else if (k == 8) v0 = b_ih[n] + b_hh[n];
      f0[j] = (short)f2bf(v0);
      f1[j] = (short)f2bf(W_hh[n * 64 + k]);
      f2[j] = (short)f2bf(W_hh[n * 64 + 32 + k]);
    }
    a0[g] = f0; a1[g] = f1; a2[g] = f2;
  }

  // ---- LDS init: h0 = 0 (both bufs); x constant channels once per buf ----
  for (int i = tid; i < 2 * R * HP; i += 256) ((u16*)h_lds)[i] = 0;
  {  // 256 threads <-> 2 bufs x 32 tt x 4 rows
    const int buf = tid >> 7, rem = tid & 127, tt = rem >> 2, rr = rem & 3;
    u16* p = &x_lds[buf][tt][rr][0];
    p[8] = 0x3f80;  // bias channel = 1.0
    for (int chn = 9; chn < 32; ++chn) p[chn] = 0;
  }

  // ---- x staging: 1 float4/thread/chunk, double-buffered ----
  float4v xr;
  const int sr = tid >> 6, sm = tid & 63;          // src row, float4 idx
  const int stt = sm >> 1, sch = (sm & 1) * 4;     // dest tt, channel
  auto stage_load = [&](int chunk) {
    const float* src = x + ((size_t)bBase + sr) * (T_LEN * 8) +
                       (size_t)chunk * (TS * 8);
    xr = *(const float4v*)&src[sm * 4];
  };
  auto stage_write = [&](int buf) {
    u32 lo, hi;
    asm("v_cvt_pk_bf16_f32 %0, %1, %2" : "=v"(lo) : "v"(xr[0]), "v"(xr[1]));
    asm("v_cvt_pk_bf16_f32 %0, %1, %2" : "=v"(hi) : "v"(xr[2]), "v"(xr[3]));
    const u64 p = ((u64)hi << 32) | (u64)lo;
    *(u64*)&x_lds[buf][stt][sr][sch] = p;
  };

  stage_load(0);
  stage_write(0);
  __syncthreads();

  // ---- ANTI-PHASE SEED: one-time ~384cy stagger for half the blocks ----
  // Splits co-resident pairs whether the CU pairing is (i, i+256) (XCD
  // round-robin, differs in bit 8) or (2i, 2i+1) (differs in bit 0).
  if (((blockIdx.x ^ (blockIdx.x >> 8)) & 1) != 0)
    __builtin_amdgcn_s_sleep(6);  // 6*64 = 384 cycles, once

  // hoisted select masks for the cndmask tree
  const bool sel1 = (rsel & 1) != 0;
  const bool sel2 = (rsel & 2) != 0;
  float c = 0.f;

  for (int ch = 0; ch < T_LEN / TS; ++ch) {
    const int xb = ch & 1;
    const bool more = (ch < T_LEN / TS - 1);
#pragma unroll
    for (int tt = 0; tt < TS; ++tt) {
      const int t = ch * TS + tt;
      const int hb = t & 1;  // == tt & 1 (TS even); compile-time under unroll
      if (tt == 0 && more) stage_load(ch + 1);  // reg loads; drain in stage_write

      // ---- B fragments (uniform b128 reads) ----
      const short8v fx  = *(const short8v*)&x_lds[xb][tt][row][8 * g4];
      const short8v fh0 = *(const short8v*)&h_lds[hb][row][8 * g4];
      const short8v fh1 = *(const short8v*)&h_lds[hb][row][32 + 8 * g4];

      // ---- 12 MFMAs: 4 gate-quads x (x | h-lo | h-hi) ----
      float4v acc[4];
#pragma unroll
      for (int g = 0; g < 4; ++g)
        acc[g] = __builtin_amdgcn_mfma_f32_16x16x32_bf16(
            a0[g], fx, (float4v){0.f, 0.f, 0.f, 0.f}, 0, 0, 0);
#pragma unroll
      for (int g = 0; g < 4; ++g)
        acc[g] = __builtin_amdgcn_mfma_f32_16x16x32_bf16(a1[g], fh0, acc[g], 0, 0, 0);
#pragma unroll
      for (int g = 0; g < 4; ++g)
        acc[g] = __builtin_amdgcn_mfma_f32_16x16x32_bf16(a2[g], fh1, acc[g], 0, 0, 0);

      // ---- pick this thread's element (reg-select tree) and activate ----
      float gsel[4];
#pragma unroll
      for (int g = 0; g < 4; ++g) {
        const float x01 = sel1 ? acc[g][1] : acc[g][0];
        const float x23 = sel1 ? acc[g][3] : acc[g][2];
        gsel[g] = sel2 ? x23 : x01;
      }
      const float iv = fsig(gsel[0]);
      const float fv = fsig(gsel[1]);
      const float gv = ftanh(gsel[2]);
      const float ov = fsig(gsel[3]);
      c = fv * c + iv * gv;
      const float h = ov * ftanh(c);
      h_lds[hb ^ 1][row][jh] = cvt_bf16(h);
      if (t == T_LEN - 1) hf[row][jh] = h;
      if (tt == TS - 1 && more) stage_write((ch + 1) & 1);
      __syncthreads();  // one barrier per step
    }
  }

  // ---- epilogue: out[b] = sigmoid(hT . fc_w + fc_b) ----
  if (tid < R) {
    float a = fc_b[0];
#pragma unroll
    for (int k = 0; k < 64; ++k) a += hf[tid][k] * fc_w[k];
    out[bBase + tid] = fsig(a);
  }
}
}  // namespace

extern "C" void kernel_launch(void* const* d_in, const int* in_sizes, int n_in,
                              void* d_out, int out_size, void* d_ws,
                              size_t ws_size, hipStream_t stream) {
  const float* x    = (const float*)d_in[0];
  const float* W_ih = (const float*)d_in[1];
  const float* W_hh = (const float*)d_in[2];
  const float* b_ih = (const float*)d_in[3];
  const float* b_hh = (const float*)d_in[4];
  const float* fc_w = (const float*)d_in[5];
  const float* fc_b = (const float*)d_in[6];
  float* out = (float*)d_out;

  const int B = in_sizes[0] / (T_LEN * 8);  // 2048
  lstm_split<<<dim3(B / R), dim3(256), 0, stream>>>(x, W_ih, W_hh, b_ih, b_hh,
                                                    fc_w, fc_b, out);
}